// Round 9
// baseline (166.140 us; speedup 1.0000x reference)
//
#include <hip/hip_runtime.h>
#include <hip/hip_fp16.h>
#include <math.h>

#define B_ 2
#define N_ 512
#define H_ 128
#define NT_ 3
#define SD_ 4
#define FD_ 5

typedef float f32x4 __attribute__((ext_vector_type(4)));
typedef unsigned int u32x4 __attribute__((ext_vector_type(4)));

// 2 MFMAs sharing one A-frag; s_nop 1 covers VALU-write -> MFMA-read hazard.
#define MFMA2(a0, a1, av, b0, b1) \
    asm("s_nop 1\n\t" \
        "v_mfma_f32_16x16x32_f16 %0, %2, %3, %0\n\t" \
        "v_mfma_f32_16x16x32_f16 %1, %2, %4, %1" \
        : "+v"(a0), "+v"(a1) : "v"(av), "v"(b0), "v"(b1))

#define MFMA16F(acc, a, b) \
    asm("s_nop 1\n\tv_mfma_f32_16x16x32_f16 %0, %1, %2, %0" \
        : "+v"(acc) : "v"(a), "v"(b))

#define PKMUL(d, a, b) \
    asm("v_pk_mul_f16 %0, %1, %2" : "=v"(d) : "v"(a), "v"(b))
#define PKSUB(d, a, b) \
    asm("v_pk_add_f16 %0, %1, %2 neg_lo:[0,1] neg_hi:[0,1]" \
        : "=v"(d) : "v"(a), "v"(b))
#define CVTPKF16(d, a, b) \
    asm("v_cvt_pkrtz_f16_f32 %0, %1, %2" : "=v"(d) : "v"(a), "v"(b))

static __device__ inline unsigned short f2h(float f) {
    return __half_as_ushort(__float2half(f));
}

// ---------------------------------------------------------------------------
// h0 = relu(feats @ W_in + b_in); extra blocks: f16 B-frag prep (main + proj)
__global__ __launch_bounds__(128) void k_input(const float* __restrict__ feats,
                                               const float* __restrict__ W_in,
                                               const float* __restrict__ b_in,
                                               float* __restrict__ hout,
                                               const float* __restrict__ We1,
                                               const float* __restrict__ We2,
                                               unsigned short* __restrict__ wfrag,
                                               unsigned short* __restrict__ wfrag2) {
    int blk = blockIdx.x, tid = threadIdx.x;
    if (blk < B_ * N_) {
        const float* f = feats + (size_t)blk * FD_;
        float acc = b_in[tid];
#pragma unroll
        for (int k = 0; k < FD_; ++k) acc += f[k] * W_in[k * H_ + tid];
        hout[(size_t)blk * H_ + tid] = fmaxf(acc, 0.f);
        return;
    }
    if (blk < B_ * N_ + 32) {
        // main-GEMM B fragments: wfrag[kb][cg][lane][8] f16, c = cg*16+lr
        int t = (blk - B_ * N_) * 128 + tid;   // < 4096
        int lane = t & 63, cg = (t >> 6) & 7, kb = t >> 9;
        int lr = lane & 15, g = lane >> 4;
        int c = cg * 16 + lr;
        unsigned o[4];
#pragma unroll
        for (int p = 0; p < 4; ++p) {
            float a = We1[(size_t)(256 + kb * 32 + 8 * g + 2 * p) * H_ + c];
            float bq = We1[(size_t)(256 + kb * 32 + 8 * g + 2 * p + 1) * H_ + c];
            o[p] = (unsigned)f2h(a) | ((unsigned)f2h(bq) << 16);
        }
        u32x4 v = {o[0], o[1], o[2], o[3]};
        *(u32x4*)(wfrag + (size_t)t * 8) = v;
        return;
    }
    {
        // proj B fragments (We2, k-rows pi-permuted for 2-ct/32c groups)
        int t = (blk - (B_ * N_ + 32)) * 128 + tid;
        if (t < 256) {
            int kb = t >> 6, lane = t & 63;
            int oc = lane & 15, g = lane >> 4;
            unsigned w[4];
#pragma unroll
            for (int p = 0; p < 4; ++p) {
                int k0 = kb * 32 + g * 8 + 2 * p;
                int k1 = k0 + 1;
                // inverse pi: k' = ch*32 + lr*2 + ct  ->  c = ch*32 + ct*16 + lr
                int c0 = ((k0 >> 5) << 5) | ((k0 & 1) << 4) | ((k0 & 31) >> 1);
                int c1 = ((k1 >> 5) << 5) | ((k1 & 1) << 4) | ((k1 & 31) >> 1);
                float v0 = (oc < 3) ? We2[c0 * 3 + oc] : 0.f;
                float v1 = (oc < 3) ? We2[c1 * 3 + oc] : 0.f;
                w[p] = (unsigned)f2h(v0) | ((unsigned)f2h(v1) << 16);
            }
            u32x4 v = {w[0], w[1], w[2], w[3]};
            *(u32x4*)(wfrag2 + (size_t)t * 8) = v;
        }
    }
}

// ---------------------------------------------------------------------------
// msg = adj @ h, 256 threads: 4-segment ballot compaction + k-split-2 gather
// and k-split-2 dense GEMV. One block per node (1024 blocks).
__global__ __launch_bounds__(256) void k_mp(const float* __restrict__ hin,
                                            float* __restrict__ hout,
                                            const float* __restrict__ adj,
                                            const float* __restrict__ Wl,
                                            const float* __restrict__ bl) {
    __shared__ float xbuf[256];              // [hi | msg]
    __shared__ unsigned short idxs[512];
    __shared__ float avals[512];
    __shared__ float red[256];
    __shared__ int cnt[4];
    int node = blockIdx.x;      // b*N + i
    int b = node >> 9;
    int tid = threadIdx.x;
    int w = tid >> 6, lane = tid & 63;
    if (tid < 128) xbuf[tid] = hin[(size_t)node * H_ + tid];
    const float* arow = adj + (size_t)node * N_;
    float2 av = ((const float2*)arow)[tid];   // j = 2*tid, 2*tid+1
    int cum = 0;
#pragma unroll
    for (int q2 = 0; q2 < 2; ++q2) {
        float a = (&av.x)[q2];
        bool pred = (a != 0.f);
        unsigned long long mask = __ballot(pred);
        if (pred) {
            int pos = 128 * w + cum +
                      (int)__popcll(mask & ((1ull << lane) - 1ull));
            idxs[pos] = (unsigned short)(2 * tid + q2);
            avals[pos] = a;
        }
        cum += (int)__popcll(mask);
    }
    if (lane == 0) cnt[w] = cum;
    __syncthreads();

    int c = tid & 127, q = tid >> 7;
    const float* hb = hin + ((size_t)b * N_) * H_;
    float m = 0.f;
#pragma unroll
    for (int s = 0; s < 4; ++s) {
        int ns = cnt[s];
        for (int t = q; t < ns; t += 2)
            m += avals[128 * s + t] * hb[(size_t)idxs[128 * s + t] * H_ + c];
    }
    red[q * 128 + c] = m;
    __syncthreads();
    if (q == 0) xbuf[128 + c] = red[c] + red[128 + c];
    __syncthreads();

    float acc = 0.f;
#pragma unroll 4
    for (int k = 128 * q; k < 128 * q + 128; ++k)
        acc += xbuf[k] * Wl[(size_t)k * H_ + c];
    red[q * 128 + c] = acc;
    __syncthreads();
    if (q == 0)
        hout[(size_t)node * H_ + c] =
            fmaxf(red[c] + red[128 + c] + bl[c], 0.f);
}

// ---------------------------------------------------------------------------
// heads + pi-scattered per-node precomputes A_i (incl be1), B_j, f16 h copy
__global__ __launch_bounds__(128) void k_heads(
    const float* __restrict__ h, const float* __restrict__ feats,
    const float* __restrict__ snm,
    const float* __restrict__ Wt1, const float* __restrict__ bt1,
    const float* __restrict__ Wt2, const float* __restrict__ bt2,
    const float* __restrict__ Ws1, const float* __restrict__ bs1,
    const float* __restrict__ Ws2, const float* __restrict__ bs2,
    const float* __restrict__ We1, const float* __restrict__ be1,
    float* __restrict__ Acoef, float* __restrict__ Bcoef,
    unsigned short* __restrict__ hf16,
    float* __restrict__ type_out, float* __restrict__ state_out) {
    __shared__ float hi[H_], hT[H_], hS[H_];
    int node = blockIdx.x, tid = threadIdx.x;
    float hv0 = h[(size_t)node * H_ + tid];
    hi[tid] = hv0;
    hf16[(size_t)node * H_ + tid] = f2h(hv0);
    __syncthreads();
    float at = bt1[tid], as = bs1[tid], aa = be1[tid], ab = 0.f;
#pragma unroll 4
    for (int k = 0; k < H_; ++k) {
        float hv = hi[k];
        at += hv * Wt1[k * H_ + tid];
        as += hv * Ws1[k * H_ + tid];
        aa += hv * We1[k * H_ + tid];            // W_a rows [0,128)
        ab += hv * We1[(k + H_) * H_ + tid];     // W_b rows [128,256)
    }
    hT[tid] = fmaxf(at, 0.f);
    hS[tid] = fmaxf(as, 0.f);
    // pi-position (2-ct/32c): c = ch*32 + ct*16 + lr -> k' = ch*32 + lr*2 + ct
    int c = tid;
    int kp = ((c >> 5) << 5) | ((c & 15) << 1) | ((c >> 4) & 1);
    Acoef[(size_t)node * H_ + kp] = aa;
    Bcoef[(size_t)node * H_ + kp] = ab;
    __syncthreads();
    float sm = snm[node];
    if (tid < NT_) {
        float tl = bt2[tid];
        for (int cc = 0; cc < H_; ++cc) tl += hT[cc] * Wt2[cc * NT_ + tid];
        int ct = (int)feats[(size_t)node * FD_];
        ct = ct < 0 ? 0 : (ct > NT_ - 1 ? NT_ - 1 : ct);
        float cv = (tid == ct) ? 10.f : -10.f;
        type_out[(size_t)node * NT_ + tid] = (sm != 0.f) ? tl : cv;
    }
    if (tid >= 64 && tid < 64 + SD_) {
        int s = tid - 64;
        float sl = bs2[s];
        for (int cc = 0; cc < H_; ++cc) sl += hS[cc] * Ws2[cc * SD_ + s];
        state_out[(size_t)node * SD_ + s] =
            sm * sl + (1.f - sm) * feats[(size_t)node * FD_ + 1 + s];
    }
}

// ---------------------------------------------------------------------------
// f16 fused pair kernel, 8 waves (512 thr) = 2 jh x 4 ch, ct=2 per wave so
// Bf[2][8]=64 VGPR stays REGISTER-RESIDENT (launch_bounds cap 256).
// Two-pass 64-j tile; writes symmetrized s-values into edl's upper slots.
__global__ __launch_bounds__(512, 2) void k_pair2(
    const unsigned short* __restrict__ hf16,
    const float* __restrict__ Acp, const float* __restrict__ Bcp,
    const unsigned short* __restrict__ wfrag,
    const unsigned short* __restrict__ wfrag2,
    const float* __restrict__ be2,
    float* __restrict__ edl_out) {

    __shared__ unsigned short tile[2][64][128];   // 32KB pi-packed f16
    __shared__ float sbuf[2][64][3];              // 1.5KB proj outputs

    int bid = blockIdx.x;
    int b = 0, r = bid;
    if (r >= 1280) { b = 1; r -= 1280; }
    int jtile, i;
    if (r < 128)      { jtile = 0; i = r; }
    else if (r < 384) { jtile = 1; i = r - 128; }
    else if (r < 768) { jtile = 2; i = r - 384; }
    else              { jtile = 3; i = r - 768; }
    int JT0 = jtile << 7;
    int bN = b << 9;

    int tid = threadIdx.x;
    int wave = tid >> 6, lane = tid & 63;
    int jh = wave >> 2, ch = wave & 3;
    int lr = lane & 15, g = lane >> 4;

    // main-GEMM B fragments: 2 ct (cg = ch*2+ct) x 8 kb = 64 VGPR, resident
    u32x4 Bf[2][8];
#pragma unroll
    for (int ct = 0; ct < 2; ++ct)
#pragma unroll
        for (int kb = 0; kb < 8; ++kb)
            Bf[ct][kb] = *(const u32x4*)(wfrag +
                (((size_t)kb * 8 + (ch * 2 + ct)) * 64 + lane) * 8);

    // proj B-frags (pre-permuted We2, f16)
    u32x4 Bf2[4];
#pragma unroll
    for (int kb = 0; kb < 4; ++kb)
        Bf2[kb] = *(const u32x4*)(wfrag2 + ((size_t)kb * 64 + lane) * 8);

    // hi fragments pre-packed from hf16 (same rounding as hj side)
    const unsigned short* hirow = hf16 + (size_t)(bN + i) * H_;
    u32x4 him[4];
#pragma unroll
    for (int m = 0; m < 4; ++m)
        him[m] = *(const u32x4*)(hirow + 32 * m + 8 * g);

    float2 AcoI = *(const float2*)(Acp + (size_t)(bN + i) * H_ + ch * 32 + lr * 2);
    float2 BcoI = *(const float2*)(Bcp + (size_t)(bN + i) * H_ + ch * 32 + lr * 2);

    char* tb0 = (char*)&tile[0][0][0];
    char* tb1 = (char*)&tile[1][0][0];

    for (int jhalf = 0; jhalf < 2; ++jhalf) {
        int J0 = JT0 + jhalf * 64;
#pragma unroll
        for (int jt = 0; jt < 2; ++jt) {
            int jloc0 = jh * 32 + jt * 16;            // local row 0..63
            const unsigned short* hjp =
                hf16 + (size_t)(bN + J0 + jloc0 + lr) * H_ + 8 * g;
            u32x4 hjall[4];
#pragma unroll
            for (int m = 0; m < 4; ++m)
                hjall[m] = *(const u32x4*)(hjp + 32 * m);
            // prefetch epilogue coefs (independent of MFMAs)
            float2 BcJv[4], AcJv[4];
#pragma unroll
            for (int rr = 0; rr < 4; ++rr) {
                size_t jn = (size_t)(bN + J0 + jloc0 + 4 * g + rr) * H_ +
                            ch * 32 + lr * 2;
                BcJv[rr] = *(const float2*)(Bcp + jn);
                AcJv[rr] = *(const float2*)(Acp + jn);
            }

            f32x4 acc0 = {0.f,0.f,0.f,0.f}, acc1 = {0.f,0.f,0.f,0.f};

#pragma unroll
            for (int m = 0; m < 4; ++m) {
                u32x4 tav, uav;
#pragma unroll
                for (int p = 0; p < 4; ++p) {
                    unsigned hip_ = him[m][p], hjp_ = hjall[m][p];
                    unsigned u_, d_;
                    PKMUL(u_, hip_, hjp_);
                    PKSUB(d_, hip_, hjp_);
                    uav[p] = u_;
                    tav[p] = d_ & 0x7fff7fffu;
                }
                MFMA2(acc0, acc1, tav, Bf[0][m], Bf[1][m]);
                MFMA2(acc0, acc1, uav, Bf[0][4 + m], Bf[1][4 + m]);
            }
            asm("s_nop 7\n\ts_nop 7\n\ts_nop 3" : "+v"(acc0), "+v"(acc1));

            // both orientations' hidden, pi-packed f16 into swizzled LDS
#pragma unroll
            for (int rr = 0; rr < 4; ++rr) {
                int jloc = jloc0 + 4 * g + rr;
                float h10 = fmaxf(acc0[rr] + AcoI.x + BcJv[rr].x, 0.f);
                float h11 = fmaxf(acc1[rr] + AcoI.y + BcJv[rr].y, 0.f);
                float h20 = fmaxf(acc0[rr] + AcJv[rr].x + BcoI.x, 0.f);
                float h21 = fmaxf(acc1[rr] + AcJv[rr].y + BcoI.y, 0.f);
                unsigned w1, w2;
                CVTPKF16(w1, h10, h11);
                CVTPKF16(w2, h20, h21);
                int byte = jloc * 256 + ch * 64 + lr * 4;
                byte ^= (jloc & 7) << 4;
                *(unsigned*)(tb0 + byte) = w1;
                *(unsigned*)(tb1 + byte) = w2;
            }
        }
        __syncthreads();

        // projection MFMAs: 8 subtiles (2 orient x 4 of 16 rows), 1 per wave
        {
            int orient = wave >> 2, sub = wave & 3;
            char* tb = orient ? tb1 : tb0;
            int jloc = sub * 16 + lr;
            f32x4 pacc = {0.f, 0.f, 0.f, 0.f};
#pragma unroll
            for (int kb = 0; kb < 4; ++kb) {
                int byte = jloc * 256 + kb * 64 + g * 16;
                byte ^= (jloc & 7) << 4;
                u32x4 a = *(const u32x4*)(tb + byte);
                MFMA16F(pacc, a, Bf2[kb]);
            }
            asm("s_nop 7\n\ts_nop 7\n\ts_nop 3" : "+v"(pacc));
            if (lr < 3) {
#pragma unroll
                for (int rr = 0; rr < 4; ++rr)
                    sbuf[orient][sub * 16 + 4 * g + rr][lr] = pacc[rr];
            }
        }
        __syncthreads();

        // symmetrized s (+be2) -> edl row i, cols J0..J0+63 (768B contiguous)
        if (tid < 192) {
            int jloc = tid / 3, comp = tid - jloc * 3;
            float v = 0.5f * (sbuf[0][jloc][comp] + sbuf[1][jloc][comp]) +
                      be2[comp];
            edl_out[((size_t)(bN + i) * N_ + (J0 + jloc)) * 3 + comp] = v;
        }
    }
}

// ---------------------------------------------------------------------------
// Transpose + mask + decode. One block per unordered 16x16 tile pair (I<=J).
__global__ __launch_bounds__(256) void k_tr(float* __restrict__ edl,
                                            float* __restrict__ el,
                                            const float* __restrict__ sem,
                                            const float* __restrict__ adj) {
    __shared__ float ss[3][16][17];
    int tid = threadIdx.x;
    int r = tid >> 4, c = tid & 15;
    int bid = blockIdx.x;
    int b = 0, t = bid;
    if (t >= 528) { b = 1; t -= 528; }
    int J = (int)((sqrtf(8.f * (float)t + 1.f) - 1.f) * 0.5f);
    while ((J + 1) * (J + 2) / 2 <= t) ++J;
    while (J * (J + 1) / 2 > t) --J;
    int I = t - J * (J + 1) / 2;
    int i0 = I * 16, j0 = J * 16;
    int bN = b << 9;

    {
        const float* src = edl + ((size_t)(bN + i0 + r) * N_ + (j0 + c)) * 3;
        ss[0][r][c] = src[0];
        ss[1][r][c] = src[1];
        ss[2][r][c] = src[2];
    }
    __syncthreads();

    for (int pass = 0; pass < 2; ++pass) {
        if (pass == 1 && I == J) break;
        int gi, gj;
        float s0, s1, s2;
        if (I == J) {
            gi = i0 + r; gj = j0 + c;
            int lo = r <= c ? r : c, hi = r <= c ? c : r;
            s0 = ss[0][lo][hi]; s1 = ss[1][lo][hi]; s2 = ss[2][lo][hi];
        } else if (pass == 0) {
            gi = i0 + r; gj = j0 + c;
            s0 = ss[0][r][c]; s1 = ss[1][r][c]; s2 = ss[2][r][c];
        } else {
            gi = j0 + r; gj = i0 + c;
            s0 = ss[0][c][r]; s1 = ss[1][c][r]; s2 = ss[2][c][r];
        }
        size_t p = (size_t)(bN + gi) * N_ + gj;
        if (gi == gj) {
            edl[p * 3 + 0] = 0.f; edl[p * 3 + 1] = 0.f; edl[p * 3 + 2] = 0.f;
            el[p] = -1e9f;
        } else {
            float msk = sem[p];
            float e0 = (msk != 0.f) ? s0 : 10.f;
            float e1 = (msk != 0.f) ? s1 : -10.f;
            float e2 = (msk != 0.f) ? s2 : -10.f;
            edl[p * 3 + 0] = e0; edl[p * 3 + 1] = e1; edl[p * 3 + 2] = e2;
            float a = adj[p];
            float cur = (a > 0.5f) ? 1.f : 0.f;
            float mx = fmaxf(e0, fmaxf(e1, e2));
            float x0 = expf(e0 - mx), x1 = expf(e1 - mx), x2 = expf(e2 - mx);
            float inv = 1.f / (x0 + x1 + x2);
            float pn = x1 * inv + x0 * inv * cur;
            pn = fminf(fmaxf(pn, 1e-6f), 1.f - 1e-6f);
            el[p] = logf(pn) - log1pf(-pn);
        }
    }
}

// ---------------------------------------------------------------------------
extern "C" void kernel_launch(void* const* d_in, const int* in_sizes, int n_in,
                              void* d_out, int out_size, void* d_ws,
                              size_t ws_size, hipStream_t stream) {
    const float* feats = (const float*)d_in[0];
    const float* adj   = (const float*)d_in[1];
    const float* snm   = (const float*)d_in[2];
    const float* sem   = (const float*)d_in[3];
    const float* W_in  = (const float*)d_in[4];
    const float* b_in  = (const float*)d_in[5];
    const float* W_mp  = (const float*)d_in[6];
    const float* b_mp  = (const float*)d_in[7];
    const float* Wt1 = (const float*)d_in[8],  *bt1 = (const float*)d_in[9];
    const float* Wt2 = (const float*)d_in[10], *bt2 = (const float*)d_in[11];
    const float* Ws1 = (const float*)d_in[12], *bs1 = (const float*)d_in[13];
    const float* Ws2 = (const float*)d_in[14], *bs2 = (const float*)d_in[15];
    const float* We1 = (const float*)d_in[16], *be1 = (const float*)d_in[17];
    const float* We2 = (const float*)d_in[18], *be2 = (const float*)d_in[19];

    float* out = (float*)d_out;
    float* type_out  = out;                       // B*N*NT  = 3072
    float* state_out = out + 3072;                // B*N*SD  = 4096
    float* edl_out   = out + 7168;                // B*N*N*3 = 1572864
    float* el_out    = out + 7168 + 1572864;      // B*N*N   = 524288

    float* ws = (float*)d_ws;
    float* hA = ws;                               // 131072 f (h ping -> Acp)
    float* hB = ws + 131072;                      // 131072 f (final h)
    float* Bcp = ws + 262144;                     // 131072 f
    unsigned short* hf16   = (unsigned short*)(ws + 393216);  // 131072 f16
    unsigned short* wfrag  = (unsigned short*)(ws + 458752);  // 32768 f16
    unsigned short* wfrag2 = (unsigned short*)(ws + 475136);  // 2048 f16
    float* Acp = hA;                              // reuse (dead after mp3)

    k_input<<<B_ * N_ + 34, 128, 0, stream>>>(feats, W_in, b_in, hA,
                                              We1, We2, wfrag, wfrag2);
    k_mp<<<B_ * N_, 256, 0, stream>>>(hA, hB, adj,
                                      W_mp + 0 * 2 * H_ * H_, b_mp + 0 * H_);
    k_mp<<<B_ * N_, 256, 0, stream>>>(hB, hA, adj,
                                      W_mp + 1 * 2 * H_ * H_, b_mp + 1 * H_);
    k_mp<<<B_ * N_, 256, 0, stream>>>(hA, hB, adj,
                                      W_mp + 2 * 2 * H_ * H_, b_mp + 2 * H_);
    k_heads<<<B_ * N_, H_, 0, stream>>>(hB, feats, snm, Wt1, bt1, Wt2, bt2,
                                        Ws1, bs1, Ws2, bs2, We1, be1,
                                        Acp, Bcp, hf16, type_out, state_out);
    k_pair2<<<2560, 512, 0, stream>>>(hf16, Acp, Bcp, wfrag, wfrag2,
                                      be2, edl_out);
    k_tr<<<1056, 256, 0, stream>>>(edl_out, el_out, sem, adj);
}

// Round 11
// 128.370 us; speedup vs baseline: 1.2942x; 1.2942x over previous
//
#include <hip/hip_runtime.h>
#include <hip/hip_fp16.h>
#include <math.h>

#define B_ 2
#define N_ 512
#define H_ 128
#define NT_ 3
#define SD_ 4
#define FD_ 5

typedef float f32x4 __attribute__((ext_vector_type(4)));
typedef unsigned int u32x4 __attribute__((ext_vector_type(4)));
typedef _Float16 f16x8 __attribute__((ext_vector_type(8)));
typedef __fp16 hf16x2 __attribute__((ext_vector_type(2)));

#define MFMA(acc, a, b) \
    acc = __builtin_amdgcn_mfma_f32_16x16x32_f16((a), (b), (acc), 0, 0, 0)

static __device__ inline unsigned cvt_pk_u32(float a, float b) {
    hf16x2 v = __builtin_amdgcn_cvt_pkrtz(a, b);
    return __builtin_bit_cast(unsigned, v);
}

static __device__ inline unsigned short f2h(float f) {
    return __half_as_ushort(__float2half(f));
}

// ---------------------------------------------------------------------------
// h0 = relu(feats @ W_in + b_in); extra blocks: f16 B-frag prep (main + proj)
__global__ __launch_bounds__(128) void k_input(const float* __restrict__ feats,
                                               const float* __restrict__ W_in,
                                               const float* __restrict__ b_in,
                                               float* __restrict__ hout,
                                               const float* __restrict__ We1,
                                               const float* __restrict__ We2,
                                               unsigned short* __restrict__ wfrag,
                                               unsigned short* __restrict__ wfrag2) {
    int blk = blockIdx.x, tid = threadIdx.x;
    if (blk < B_ * N_) {
        const float* f = feats + (size_t)blk * FD_;
        float acc = b_in[tid];
#pragma unroll
        for (int k = 0; k < FD_; ++k) acc += f[k] * W_in[k * H_ + tid];
        hout[(size_t)blk * H_ + tid] = fmaxf(acc, 0.f);
        return;
    }
    if (blk < B_ * N_ + 32) {
        // main-GEMM B fragments: wfrag[kb][cg][lane][8] f16, c = cg*16+lr
        int t = (blk - B_ * N_) * 128 + tid;   // < 4096
        int lane = t & 63, cg = (t >> 6) & 7, kb = t >> 9;
        int lr = lane & 15, g = lane >> 4;
        int c = cg * 16 + lr;
        unsigned o[4];
#pragma unroll
        for (int p = 0; p < 4; ++p) {
            float a = We1[(size_t)(256 + kb * 32 + 8 * g + 2 * p) * H_ + c];
            float bq = We1[(size_t)(256 + kb * 32 + 8 * g + 2 * p + 1) * H_ + c];
            o[p] = (unsigned)f2h(a) | ((unsigned)f2h(bq) << 16);
        }
        u32x4 v = {o[0], o[1], o[2], o[3]};
        *(u32x4*)(wfrag + (size_t)t * 8) = v;
        return;
    }
    {
        // proj B fragments (We2, k-rows pi-permuted, 4-ct/64c groups)
        int t = (blk - (B_ * N_ + 32)) * 128 + tid;
        if (t < 256) {
            int kb = t >> 6, lane = t & 63;
            int oc = lane & 15, g = lane >> 4;
            unsigned w[4];
#pragma unroll
            for (int p = 0; p < 4; ++p) {
                int k0 = kb * 32 + g * 8 + 2 * p;
                int k1 = k0 + 1;
                int c0 = ((k0 >> 6) << 6) | ((k0 & 3) << 4) | ((k0 & 63) >> 2);
                int c1 = ((k1 >> 6) << 6) | ((k1 & 3) << 4) | ((k1 & 63) >> 2);
                float v0 = (oc < 3) ? We2[c0 * 3 + oc] : 0.f;
                float v1 = (oc < 3) ? We2[c1 * 3 + oc] : 0.f;
                w[p] = (unsigned)f2h(v0) | ((unsigned)f2h(v1) << 16);
            }
            u32x4 v = {w[0], w[1], w[2], w[3]};
            *(u32x4*)(wfrag2 + (size_t)t * 8) = v;
        }
    }
}

// ---------------------------------------------------------------------------
// msg = adj @ h via deterministic ballot-compaction (r6 known-good form)
__global__ __launch_bounds__(128) void k_mp(const float* __restrict__ hin,
                                            float* __restrict__ hout,
                                            const float* __restrict__ adj,
                                            const float* __restrict__ Wl,
                                            const float* __restrict__ bl) {
    __shared__ float hi[H_];
    __shared__ float msg[H_];
    __shared__ unsigned short idxs[N_];
    __shared__ float avals[N_];
    __shared__ int cnt2[2];
    int node = blockIdx.x;      // b*N + i
    int b = node >> 9;
    int tid = threadIdx.x;
    int w = tid >> 6, lane = tid & 63;
    hi[tid] = hin[(size_t)node * H_ + tid];
    const float* arow = adj + (size_t)node * N_;
    float4 av = ((const float4*)arow)[tid];
    int segbase = w * 256;
    int cum = 0;
#pragma unroll
    for (int q = 0; q < 4; ++q) {
        float a = (&av.x)[q];
        bool pred = (a != 0.f);
        unsigned long long mask = __ballot(pred);
        if (pred) {
            int pos = segbase + cum +
                      (int)__popcll(mask & ((1ull << lane) - 1ull));
            idxs[pos] = (unsigned short)(tid * 4 + q);
            avals[pos] = a;
        }
        cum += (int)__popcll(mask);
    }
    if (lane == 0) cnt2[w] = cum;
    __syncthreads();

    float m = 0.f;
    const float* hb = hin + ((size_t)b * N_) * H_;
    int n0 = cnt2[0], n1 = cnt2[1];
    for (int t = 0; t < n0; ++t)
        m += avals[t] * hb[(size_t)idxs[t] * H_ + tid];
    for (int t = 0; t < n1; ++t)
        m += avals[256 + t] * hb[(size_t)idxs[256 + t] * H_ + tid];
    msg[tid] = m;
    __syncthreads();

    float acc = bl[tid];
#pragma unroll 4
    for (int k = 0; k < H_; ++k) {
        acc += hi[k]  * Wl[(size_t)k * H_ + tid];
        acc += msg[k] * Wl[(size_t)(k + H_) * H_ + tid];
    }
    hout[(size_t)node * H_ + tid] = fmaxf(acc, 0.f);
}

// ---------------------------------------------------------------------------
// heads + pi-scattered per-node precomputes A_i (incl be1), B_j, f16 h copy
__global__ __launch_bounds__(128) void k_heads(
    const float* __restrict__ h, const float* __restrict__ feats,
    const float* __restrict__ snm,
    const float* __restrict__ Wt1, const float* __restrict__ bt1,
    const float* __restrict__ Wt2, const float* __restrict__ bt2,
    const float* __restrict__ Ws1, const float* __restrict__ bs1,
    const float* __restrict__ Ws2, const float* __restrict__ bs2,
    const float* __restrict__ We1, const float* __restrict__ be1,
    float* __restrict__ Acoef, float* __restrict__ Bcoef,
    unsigned short* __restrict__ hf16,
    float* __restrict__ type_out, float* __restrict__ state_out) {
    __shared__ float hi[H_], hT[H_], hS[H_];
    int node = blockIdx.x, tid = threadIdx.x;
    float hv0 = h[(size_t)node * H_ + tid];
    hi[tid] = hv0;
    hf16[(size_t)node * H_ + tid] = f2h(hv0);
    __syncthreads();
    float at = bt1[tid], as = bs1[tid], aa = be1[tid], ab = 0.f;
#pragma unroll 4
    for (int k = 0; k < H_; ++k) {
        float hv = hi[k];
        at += hv * Wt1[k * H_ + tid];
        as += hv * Ws1[k * H_ + tid];
        aa += hv * We1[k * H_ + tid];            // W_a rows [0,128)
        ab += hv * We1[(k + H_) * H_ + tid];     // W_b rows [128,256)
    }
    hT[tid] = fmaxf(at, 0.f);
    hS[tid] = fmaxf(as, 0.f);
    // pi-position: c = ch*64 + ct*16 + lr  ->  k' = ch*64 + lr*4 + ct
    int c = tid;
    int kp = ((c >> 6) << 6) | ((c & 15) << 2) | ((c >> 4) & 3);
    Acoef[(size_t)node * H_ + kp] = aa;
    Bcoef[(size_t)node * H_ + kp] = ab;
    __syncthreads();
    float sm = snm[node];
    if (tid < NT_) {
        float tl = bt2[tid];
        for (int cc = 0; cc < H_; ++cc) tl += hT[cc] * Wt2[cc * NT_ + tid];
        int ct = (int)feats[(size_t)node * FD_];
        ct = ct < 0 ? 0 : (ct > NT_ - 1 ? NT_ - 1 : ct);
        float cv = (tid == ct) ? 10.f : -10.f;
        type_out[(size_t)node * NT_ + tid] = (sm != 0.f) ? tl : cv;
    }
    if (tid >= 64 && tid < 64 + SD_) {
        int s = tid - 64;
        float sl = bs2[s];
        for (int cc = 0; cc < H_; ++cc) sl += hS[cc] * Ws2[cc * SD_ + s];
        state_out[(size_t)node * SD_ + s] =
            sm * sl + (1.f - sm) * feats[(size_t)node * FD_ + 1 + s];
    }
}

// ---------------------------------------------------------------------------
// f16 fused pair kernel, INTRINSIC MFMAs (compiler-managed regs/AGPRs).
// 4 waves (jh x ch), ct=4; two-pass 64-j tile; writes symmetrized s-values
// into edl's upper-triangle slots (768B contiguous per pass).
__global__ __launch_bounds__(256, 2) void k_pair2(
    const unsigned short* __restrict__ hf16,
    const float* __restrict__ Acp, const float* __restrict__ Bcp,
    const unsigned short* __restrict__ wfrag,
    const unsigned short* __restrict__ wfrag2,
    const float* __restrict__ be2,
    float* __restrict__ edl_out) {

    __shared__ unsigned short tile[2][64][128];   // 32KB pi-packed f16
    __shared__ float sbuf[2][64][3];              // 1.5KB proj outputs

    int bid = blockIdx.x;
    int b = 0, r = bid;
    if (r >= 1280) { b = 1; r -= 1280; }
    int jtile, i;
    if (r < 128)      { jtile = 0; i = r; }
    else if (r < 384) { jtile = 1; i = r - 128; }
    else if (r < 768) { jtile = 2; i = r - 384; }
    else              { jtile = 3; i = r - 768; }
    int JT0 = jtile << 7;
    int bN = b << 9;

    int tid = threadIdx.x;
    int wave = tid >> 6, lane = tid & 63;
    int jh = wave >> 1, ch = wave & 1;
    int lr = lane & 15, g = lane >> 4;

    // main-GEMM B fragments: 4 ct (cg = ch*4+ct) x 8 kb
    f16x8 Bf[4][8];
#pragma unroll
    for (int ct = 0; ct < 4; ++ct)
#pragma unroll
        for (int kb = 0; kb < 8; ++kb)
            Bf[ct][kb] = *(const f16x8*)(wfrag +
                (((size_t)kb * 8 + (ch * 4 + ct)) * 64 + lane) * 8);

    // proj B-frags (pre-permuted We2, f16)
    f16x8 Bf2[4];
#pragma unroll
    for (int kb = 0; kb < 4; ++kb)
        Bf2[kb] = *(const f16x8*)(wfrag2 + ((size_t)kb * 64 + lane) * 8);

    // hi fragments pre-packed from hf16 (same rounding as hj side)
    const unsigned short* hirow = hf16 + (size_t)(bN + i) * H_;
    f16x8 him[4];
#pragma unroll
    for (int m = 0; m < 4; ++m)
        him[m] = *(const f16x8*)(hirow + 32 * m + 8 * g);

    f32x4 AcoI = *(const f32x4*)(Acp + (size_t)(bN + i) * H_ + ch * 64 + lr * 4);
    f32x4 BcoI = *(const f32x4*)(Bcp + (size_t)(bN + i) * H_ + ch * 64 + lr * 4);

    char* tb0 = (char*)&tile[0][0][0];
    char* tb1 = (char*)&tile[1][0][0];

    for (int jhalf = 0; jhalf < 2; ++jhalf) {
        int J0 = JT0 + jhalf * 64;
#pragma unroll
        for (int jt = 0; jt < 2; ++jt) {
            int jloc0 = jh * 32 + jt * 16;            // local row 0..63
            const unsigned short* hjp =
                hf16 + (size_t)(bN + J0 + jloc0 + lr) * H_ + 8 * g;
            f16x8 hjall[4];
#pragma unroll
            for (int m = 0; m < 4; ++m)
                hjall[m] = *(const f16x8*)(hjp + 32 * m);
            // prefetch epilogue coefs (independent of MFMAs)
            f32x4 BcJv[4], AcJv[4];
#pragma unroll
            for (int rr = 0; rr < 4; ++rr) {
                size_t jn = (size_t)(bN + J0 + jloc0 + 4 * g + rr) * H_ +
                            ch * 64 + lr * 4;
                BcJv[rr] = *(const f32x4*)(Bcp + jn);
                AcJv[rr] = *(const f32x4*)(Acp + jn);
            }

            f32x4 acc0 = {0.f,0.f,0.f,0.f}, acc1 = {0.f,0.f,0.f,0.f};
            f32x4 acc2 = {0.f,0.f,0.f,0.f}, acc3 = {0.f,0.f,0.f,0.f};

#pragma unroll
            for (int m = 0; m < 4; ++m) {
                f16x8 diff = him[m] - hjall[m];
                u32x4 du = __builtin_bit_cast(u32x4, diff) & 0x7fff7fffu;
                f16x8 tav = __builtin_bit_cast(f16x8, du);
                f16x8 uav = him[m] * hjall[m];
                MFMA(acc0, tav, Bf[0][m]);
                MFMA(acc1, tav, Bf[1][m]);
                MFMA(acc2, tav, Bf[2][m]);
                MFMA(acc3, tav, Bf[3][m]);
                MFMA(acc0, uav, Bf[0][4 + m]);
                MFMA(acc1, uav, Bf[1][4 + m]);
                MFMA(acc2, uav, Bf[2][4 + m]);
                MFMA(acc3, uav, Bf[3][4 + m]);
            }

            // both orientations' hidden, pi-packed f16 into swizzled LDS
#pragma unroll
            for (int rr = 0; rr < 4; ++rr) {
                int jloc = jloc0 + 4 * g + rr;
                float h10 = fmaxf(acc0[rr] + AcoI[0] + BcJv[rr][0], 0.f);
                float h11 = fmaxf(acc1[rr] + AcoI[1] + BcJv[rr][1], 0.f);
                float h12 = fmaxf(acc2[rr] + AcoI[2] + BcJv[rr][2], 0.f);
                float h13 = fmaxf(acc3[rr] + AcoI[3] + BcJv[rr][3], 0.f);
                float h20 = fmaxf(acc0[rr] + AcJv[rr][0] + BcoI[0], 0.f);
                float h21 = fmaxf(acc1[rr] + AcJv[rr][1] + BcoI[1], 0.f);
                float h22 = fmaxf(acc2[rr] + AcJv[rr][2] + BcoI[2], 0.f);
                float h23 = fmaxf(acc3[rr] + AcJv[rr][3] + BcoI[3], 0.f);
                int byte = jloc * 256 + ch * 128 + lr * 8;
                byte ^= (jloc & 7) << 4;
                uint2 v1; v1.x = cvt_pk_u32(h10, h11);
                v1.y = cvt_pk_u32(h12, h13);
                uint2 v2; v2.x = cvt_pk_u32(h20, h21);
                v2.y = cvt_pk_u32(h22, h23);
                *(uint2*)(tb0 + byte) = v1;
                *(uint2*)(tb1 + byte) = v2;
            }
        }
        __syncthreads();

        // projection MFMAs: 8 subtiles (2 orient x 4 of 16 rows), 2 per wave
        f32x4 pacc0 = {0.f,0.f,0.f,0.f}, pacc1 = {0.f,0.f,0.f,0.f};
#pragma unroll
        for (int p = 0; p < 2; ++p) {
            int f = wave + 4 * p;
            int orient = f >> 2, sub = f & 3;
            char* tb = orient ? tb1 : tb0;
            int jloc = sub * 16 + lr;
#pragma unroll
            for (int kb = 0; kb < 4; ++kb) {
                int byte = jloc * 256 + kb * 64 + g * 16;
                byte ^= (jloc & 7) << 4;
                f16x8 a = *(const f16x8*)(tb + byte);
                if (p == 0) { MFMA(pacc0, a, Bf2[kb]); }
                else        { MFMA(pacc1, a, Bf2[kb]); }
            }
        }

        if (lr < 3) {
#pragma unroll
            for (int p = 0; p < 2; ++p) {
                int f = wave + 4 * p;
                int orient = f >> 2, sub = f & 3;
                f32x4 pa = p ? pacc1 : pacc0;
#pragma unroll
                for (int rr = 0; rr < 4; ++rr) {
                    int jloc = sub * 16 + 4 * g + rr;
                    sbuf[orient][jloc][lr] = pa[rr];
                }
            }
        }
        __syncthreads();

        // symmetrized s (+be2) -> edl row i, cols J0..J0+63 (768B contiguous)
        if (tid < 192) {
            int jloc = tid / 3, comp = tid - jloc * 3;
            float v = 0.5f * (sbuf[0][jloc][comp] + sbuf[1][jloc][comp]) +
                      be2[comp];
            edl_out[((size_t)(bN + i) * N_ + (J0 + jloc)) * 3 + comp] = v;
        }
        __syncthreads();   // sbuf reuse safety for next pass
    }
}

// ---------------------------------------------------------------------------
// Transpose + mask + decode. One block per unordered 16x16 tile pair (I<=J).
__global__ __launch_bounds__(256) void k_tr(float* __restrict__ edl,
                                            float* __restrict__ el,
                                            const float* __restrict__ sem,
                                            const float* __restrict__ adj) {
    __shared__ float ss[3][16][17];
    int tid = threadIdx.x;
    int r = tid >> 4, c = tid & 15;
    int bid = blockIdx.x;
    int b = 0, t = bid;
    if (t >= 528) { b = 1; t -= 528; }
    int J = (int)((sqrtf(8.f * (float)t + 1.f) - 1.f) * 0.5f);
    while ((J + 1) * (J + 2) / 2 <= t) ++J;
    while (J * (J + 1) / 2 > t) --J;
    int I = t - J * (J + 1) / 2;
    int i0 = I * 16, j0 = J * 16;
    int bN = b << 9;

    {
        const float* src = edl + ((size_t)(bN + i0 + r) * N_ + (j0 + c)) * 3;
        ss[0][r][c] = src[0];
        ss[1][r][c] = src[1];
        ss[2][r][c] = src[2];
    }
    __syncthreads();

    for (int pass = 0; pass < 2; ++pass) {
        if (pass == 1 && I == J) break;
        int gi, gj;
        float s0, s1, s2;
        if (I == J) {
            gi = i0 + r; gj = j0 + c;
            int lo = r <= c ? r : c, hi = r <= c ? c : r;
            s0 = ss[0][lo][hi]; s1 = ss[1][lo][hi]; s2 = ss[2][lo][hi];
        } else if (pass == 0) {
            gi = i0 + r; gj = j0 + c;
            s0 = ss[0][r][c]; s1 = ss[1][r][c]; s2 = ss[2][r][c];
        } else {
            gi = j0 + r; gj = i0 + c;
            s0 = ss[0][c][r]; s1 = ss[1][c][r]; s2 = ss[2][c][r];
        }
        size_t p = (size_t)(bN + gi) * N_ + gj;
        if (gi == gj) {
            edl[p * 3 + 0] = 0.f; edl[p * 3 + 1] = 0.f; edl[p * 3 + 2] = 0.f;
            el[p] = -1e9f;
        } else {
            float msk = sem[p];
            float e0 = (msk != 0.f) ? s0 : 10.f;
            float e1 = (msk != 0.f) ? s1 : -10.f;
            float e2 = (msk != 0.f) ? s2 : -10.f;
            edl[p * 3 + 0] = e0; edl[p * 3 + 1] = e1; edl[p * 3 + 2] = e2;
            float a = adj[p];
            float cur = (a > 0.5f) ? 1.f : 0.f;
            float mx = fmaxf(e0, fmaxf(e1, e2));
            float x0 = expf(e0 - mx), x1 = expf(e1 - mx), x2 = expf(e2 - mx);
            float inv = 1.f / (x0 + x1 + x2);
            float pn = x1 * inv + x0 * inv * cur;
            pn = fminf(fmaxf(pn, 1e-6f), 1.f - 1e-6f);
            el[p] = logf(pn) - log1pf(-pn);
        }
    }
}

// ---------------------------------------------------------------------------
extern "C" void kernel_launch(void* const* d_in, const int* in_sizes, int n_in,
                              void* d_out, int out_size, void* d_ws,
                              size_t ws_size, hipStream_t stream) {
    const float* feats = (const float*)d_in[0];
    const float* adj   = (const float*)d_in[1];
    const float* snm   = (const float*)d_in[2];
    const float* sem   = (const float*)d_in[3];
    const float* W_in  = (const float*)d_in[4];
    const float* b_in  = (const float*)d_in[5];
    const float* W_mp  = (const float*)d_in[6];
    const float* b_mp  = (const float*)d_in[7];
    const float* Wt1 = (const float*)d_in[8],  *bt1 = (const float*)d_in[9];
    const float* Wt2 = (const float*)d_in[10], *bt2 = (const float*)d_in[11];
    const float* Ws1 = (const float*)d_in[12], *bs1 = (const float*)d_in[13];
    const float* Ws2 = (const float*)d_in[14], *bs2 = (const float*)d_in[15];
    const float* We1 = (const float*)d_in[16], *be1 = (const float*)d_in[17];
    const float* We2 = (const float*)d_in[18], *be2 = (const float*)d_in[19];

    float* out = (float*)d_out;
    float* type_out  = out;                       // B*N*NT  = 3072
    float* state_out = out + 3072;                // B*N*SD  = 4096
    float* edl_out   = out + 7168;                // B*N*N*3 = 1572864
    float* el_out    = out + 7168 + 1572864;      // B*N*N   = 524288

    float* ws = (float*)d_ws;
    float* hA = ws;                               // 131072 f (h ping -> Acp)
    float* hB = ws + 131072;                      // 131072 f (final h)
    float* Bcp = ws + 262144;                     // 131072 f
    unsigned short* hf16   = (unsigned short*)(ws + 393216);  // 131072 f16
    unsigned short* wfrag  = (unsigned short*)(ws + 458752);  // 32768 f16
    unsigned short* wfrag2 = (unsigned short*)(ws + 475136);  // 2048 f16
    float* Acp = hA;                              // reuse (dead after mp3)

    k_input<<<B_ * N_ + 34, 128, 0, stream>>>(feats, W_in, b_in, hA,
                                              We1, We2, wfrag, wfrag2);
    k_mp<<<B_ * N_, H_, 0, stream>>>(hA, hB, adj,
                                     W_mp + 0 * 2 * H_ * H_, b_mp + 0 * H_);
    k_mp<<<B_ * N_, H_, 0, stream>>>(hB, hA, adj,
                                     W_mp + 1 * 2 * H_ * H_, b_mp + 1 * H_);
    k_mp<<<B_ * N_, H_, 0, stream>>>(hA, hB, adj,
                                     W_mp + 2 * 2 * H_ * H_, b_mp + 2 * H_);
    k_heads<<<B_ * N_, H_, 0, stream>>>(hB, feats, snm, Wt1, bt1, Wt2, bt2,
                                        Ws1, bs1, Ws2, bs2, We1, be1,
                                        Acp, Bcp, hf16, type_out, state_out);
    k_pair2<<<2560, 256, 0, stream>>>(hf16, Acp, Bcp, wfrag, wfrag2,
                                      be2, edl_out);
    k_tr<<<1056, 256, 0, stream>>>(edl_out, el_out, sem, adj);
}